// Round 12
// baseline (98.561 us; speedup 1.0000x reference)
//
#include <hip/hip_runtime.h>

// Shapes (fixed by the reference): B=N=16, C=256, D=512, H=W=16 (HW=256)
#define B_  16
#define N_  16
#define C_  256
#define D_  512
#define HW_ 256

typedef float f32x4 __attribute__((ext_vector_type(4)));

// ws layout (float offsets)
#define WS_SP     0         // 32768 : s partials [16][8][256]
#define WS_S      32768     // 4096  : s[b,hw] (written by chunk-0 Z-blocks)
#define WS_M      36864     // 16    : per-b softmax max
#define WS_TMAX   36880     // 1
#define WS_TMIN   36881     // 1
#define WS_VFMEAN 36884     // 4096
#define WS_VPMEAN 40980     // 8192
#define WS_ZP     49172     // 512   : Z partials, 32 per b

__device__ __forceinline__ float corner(float tmax, float tmin, float smax, float smin) {
  return fmaxf(fmaxf(tmax * smax, tmax * smin), fmaxf(tmin * smax, tmin * smin));
}

// ---------------- kP: 641 blocks x 512 threads (byte-identical to R11) -----
__global__ __launch_bounds__(512)
void kP(const float* __restrict__ vf, const float* __restrict__ vw,
        const float* __restrict__ vb, const float* __restrict__ te,
        float* __restrict__ ws) {
  int bid = blockIdx.x, tid = threadIdx.x;
  int w = tid >> 6, lane = tid & 63;

  if (bid < 512) {
    int row = bid * 8 + w;                       // 0..4095
    float4 v = ((const float4*)vf)[(size_t)row * 64 + lane];
    float s4 = v.x + v.y + v.z + v.w;
    for (int m = 32; m; m >>= 1) s4 += __shfl_xor(s4, m);
    if (lane == 0) ws[WS_VFMEAN + row] = s4 * (1.0f / HW_);
    return;
  }
  if (bid == 640) {
    float mx = -1e30f, mn = 1e30f;
    #pragma unroll
    for (int i = tid; i < N_ * D_; i += 512) {
      float v = te[i];
      mx = fmaxf(mx, v); mn = fminf(mn, v);
    }
    for (int m = 32; m; m >>= 1) {
      mx = fmaxf(mx, __shfl_xor(mx, m));
      mn = fminf(mn, __shfl_xor(mn, m));
    }
    __shared__ float rx[8], rn[8];
    if (lane == 0) { rx[w] = mx; rn[w] = mn; }
    __syncthreads();
    if (tid == 0) {
      float ax = rx[0], an = rn[0];
      #pragma unroll
      for (int k = 1; k < 8; ++k) { ax = fmaxf(ax, rx[k]); an = fminf(an, rn[k]); }
      ws[WS_TMAX] = ax; ws[WS_TMIN] = an;
    }
    return;
  }
  {
    int sidx = bid - 512;                        // 0..127
    int b = sidx >> 3, cc = sidx & 7;
    __shared__ float pcw[16][32];
    __shared__ float cw[32];
    __shared__ float sp2[2][256];
    __shared__ float sbr[8];

    if (cc == 0) {
      float v = vb[tid];
      for (int m = 32; m; m >>= 1) v += __shfl_xor(v, m);
      if (lane == 0) sbr[w] = v;
    }
    {
      int cl = tid & 31, dg = tid >> 5;
      int c = cc * 32 + cl;
      float a = 0.f;
      #pragma unroll 8
      for (int d = dg * 32; d < dg * 32 + 32; ++d) a += vw[d * C_ + c];
      pcw[dg][cl] = a;
    }
    __syncthreads();
    if (tid < 32) {
      float a = 0.f;
      #pragma unroll
      for (int k = 0; k < 16; ++k) a += pcw[k][tid];
      cw[tid] = a;
    }
    __syncthreads();
    {
      int hw = tid & 255, hf = tid >> 8;
      const float* vfb = vf + (size_t)b * C_ * HW_ + (size_t)(cc * 32 + hf * 16) * HW_;
      float acc = 0.f;
      #pragma unroll
      for (int k = 0; k < 16; ++k) acc += vfb[k * HW_ + hw] * cw[hf * 16 + k];
      sp2[hf][hw] = acc;
    }
    __syncthreads();
    if (tid < 256) {
      float s = sp2[0][tid] + sp2[1][tid];
      if (cc == 0) {
        float sbt = sbr[0];
        #pragma unroll
        for (int k = 1; k < 8; ++k) sbt += sbr[k];
        s += sbt;
      }
      ws[WS_SP + (b * 8 + cc) * 256 + tid] = s;
    }
  }
}

// ---------------- kZ: 544 blocks x 256 threads (byte-identical to R11) -----
__global__ __launch_bounds__(256)
void kZ(const float* __restrict__ vw, const float* __restrict__ vb,
        const float* __restrict__ te, float* __restrict__ ws) {
  int bid = blockIdx.x, tid = threadIdx.x;
  if (bid < 512) {
    int b = bid >> 5, chunk = bid & 31;
    __shared__ __align__(16) float sl[HW_];
    __shared__ float r3[4], r4[4], part[4];
    float sv = 0.f;
    #pragma unroll
    for (int p = 0; p < 8; ++p) sv += ws[WS_SP + (b * 8 + p) * 256 + tid];
    sl[tid] = sv;
    float smx = sv, smn = sv;
    for (int m = 32; m; m >>= 1) {
      smx = fmaxf(smx, __shfl_xor(smx, m));
      smn = fminf(smn, __shfl_xor(smn, m));
    }
    int w = tid >> 6;
    if ((tid & 63) == 0) { r3[w] = smx; r4[w] = smn; }
    __syncthreads();
    smx = fmaxf(fmaxf(r3[0], r3[1]), fmaxf(r3[2], r3[3]));
    smn = fminf(fminf(r4[0], r4[1]), fminf(r4[2], r4[3]));
    float m = corner(ws[WS_TMAX], ws[WS_TMIN], smx, smn);
    if (chunk == 0) {
      ws[WS_S + b * HW_ + tid] = sv;
      if (tid == 0) ws[WS_M + b] = m;
    }
    float t = te[chunk * 256 + tid];
    const f32x4* sl4 = (const f32x4*)sl;
    float a0 = 0.f, a1 = 0.f, a2 = 0.f, a3 = 0.f;
    #pragma unroll 8
    for (int h = 0; h < HW_ / 4; ++h) {
      f32x4 s4 = sl4[h];
      a0 += __expf(t * s4.x - m);
      a1 += __expf(t * s4.y - m);
      a2 += __expf(t * s4.z - m);
      a3 += __expf(t * s4.w - m);
    }
    float z = (a0 + a1) + (a2 + a3);
    for (int mm = 32; mm; mm >>= 1) z += __shfl_xor(z, mm);
    if ((tid & 63) == 0) part[tid >> 6] = z;
    __syncthreads();
    if (tid == 0) ws[WS_ZP + bid] = part[0] + part[1] + part[2] + part[3];
    return;
  }
  {
    int id = (bid - 512) * 256 + tid;
    int b = id >> 9, dd = id & (D_ - 1);
    __shared__ __align__(16) float vfm[C_];
    vfm[tid] = ws[WS_VFMEAN + b * C_ + tid];
    __syncthreads();
    float acc = vb[dd];
    const f32x4* row4 = (const f32x4*)(vw + (size_t)dd * C_);
    const f32x4* v4   = (const f32x4*)vfm;
    #pragma unroll 8
    for (int c4 = 0; c4 < C_ / 4; ++c4) {
      f32x4 wv = row4[c4], av = v4[c4];
      acc += av.x * wv.x + av.y * wv.y + av.z * wv.z + av.w * wv.w;
    }
    ws[WS_VPMEAN + id] = acc;
  }
}

// ---------------- kD: 1040 blocks x 512 threads ----------------
// blocks 0..15  : final for b (512 threads = 512 d's, direct loads)
// blocks 16..1039: attn, 128 rows per block, plain f32x4 stores
__global__ __launch_bounds__(512)
void kD(const float* __restrict__ te, const float* __restrict__ mtf,
        const float* __restrict__ iw, const float* __restrict__ ib,
        const float* __restrict__ ws, float* __restrict__ out) {
  int bid = blockIdx.x, tid = threadIdx.x;
  if (bid < 16) {
    int b = bid, d = tid;
    __shared__ __align__(16) float a[D_], p[D_];
    a[tid] = mtf[b * D_ + tid];
    p[tid] = ws[WS_VPMEAN + b * D_ + tid];
    __syncthreads();
    float acc = ib[d];
    const f32x4* row4 = (const f32x4*)(iw + (size_t)d * (2 * D_));
    const f32x4* a4 = (const f32x4*)a;
    const f32x4* p4 = (const f32x4*)p;
    #pragma unroll 8
    for (int c4 = 0; c4 < D_ / 4; ++c4) {
      f32x4 w1 = row4[c4],            av = a4[c4];
      f32x4 w2 = row4[D_ / 4 + c4],   pv = p4[c4];
      acc += av.x * w1.x + av.y * w1.y + av.z * w1.z + av.w * w1.w;
      acc += pv.x * w2.x + pv.y * w2.y + pv.z * w2.z + pv.w * w2.w;
    }
    out[b * D_ + d] = acc;
    return;
  }
  // attn: 1024 blocks x 128 rows each (never straddles a b: 8192/128 = 64)
  int r0 = (bid - 16) * 128;
  int b = r0 >> 13;
  __shared__ __align__(16) float sl[HW_];
  __shared__ float sinvZ;
  if (tid < 256) sl[tid] = ws[WS_S + b * HW_ + tid];
  if (tid < 32) {
    float pz = ws[WS_ZP + b * 32 + tid];
    #pragma unroll
    for (int m = 16; m; m >>= 1) pz += __shfl_xor(pz, m);
    if (tid == 0) sinvZ = 1.0f / pz;
  }
  __syncthreads();
  float m = ws[WS_M + b];
  float invZ = sinvZ;
  int lane = tid & 63;
  int w = tid >> 6;
  float4 sv = ((const float4*)sl)[lane];
  float* attn = out + N_ * D_;
  #pragma unroll 4
  for (int k = 0; k < 16; ++k) {
    int row = r0 + w + k * 8;          // 8 waves cover 8 consecutive rows
    float t = te[row & (N_ * D_ - 1)];
    f32x4 o;
    o.x = __expf(t * sv.x - m) * invZ;
    o.y = __expf(t * sv.y - m) * invZ;
    o.z = __expf(t * sv.z - m) * invZ;
    o.w = __expf(t * sv.w - m) * invZ;
    ((f32x4*)(attn + (size_t)row * HW_))[lane] = o;
  }
}

extern "C" void kernel_launch(void* const* d_in, const int* in_sizes, int n_in,
                              void* d_out, int out_size, void* d_ws, size_t ws_size,
                              hipStream_t stream) {
  const float* mtf = (const float*)d_in[0];  // masked_text_features [16,512]
  const float* vf  = (const float*)d_in[1];  // visual_features [16,256,16,16]
  const float* te  = (const float*)d_in[2];  // text_embeddings [16,512]
  const float* vw  = (const float*)d_in[3];  // visual_proj_w [512,256]
  const float* vb  = (const float*)d_in[4];  // visual_proj_b [512]
  const float* iw  = (const float*)d_in[5];  // interaction_w [512,1024]
  const float* ib  = (const float*)d_in[6];  // interaction_b [512]
  float* out = (float*)d_out;
  float* ws  = (float*)d_ws;

  kP<<<641,  512, 0, stream>>>(vf, vw, vb, te, ws);
  kZ<<<544,  256, 0, stream>>>(vw, vb, te, ws);
  kD<<<1040, 512, 0, stream>>>(te, mtf, iw, ib, ws, out);
}

// Round 13
// 49.817 us; speedup vs baseline: 1.9785x; 1.9785x over previous
//
#include <hip/hip_runtime.h>

// Shapes (fixed by the reference): B=N=16, C=256, D=512, H=W=16 (HW=256)
#define B_  16
#define N_  16
#define C_  256
#define D_  512
#define HW_ 256

typedef float f32x4 __attribute__((ext_vector_type(4)));

// ws layout (float offsets)
#define WS_SP     0         // 32768 : s partials [16][8][256]
#define WS_S      32768     // 4096  : s[b,hw]
#define WS_M      36864     // 16    : per-b softmax max
#define WS_TMAX   36880     // 1
#define WS_TMIN   36881     // 1
#define WS_VFMEAN 36884     // 4096
#define WS_VPMEAN 40980     // 8192
#define WS_ZP     49172     // 512   : Z partials, 32 per b
#define WS_IWT    65536     // 1024x512 : iw transposed [c][d]
#define WS_VWT    589824    // 256x512  : vw transposed [c][d]

__device__ __forceinline__ float corner(float tmax, float tmin, float smax, float smin) {
  return fmaxf(fmaxf(tmax * smax, tmax * smin), fmaxf(tmin * smax, tmin * smin));
}

// ---------------- kP: 721 blocks x 512 threads ----------------
// blocks 0..511  : vfmean (8 rows/block)
// blocks 512..639: s-partials
// block 640      : te min/max
// blocks 641..704: iw transpose (2 x 64x64 tiles per block) -> WS_IWT
// blocks 705..720: vw transpose (2 tiles per block)         -> WS_VWT
__global__ __launch_bounds__(512)
void kP(const float* __restrict__ vf, const float* __restrict__ vw,
        const float* __restrict__ vb, const float* __restrict__ te,
        const float* __restrict__ iw, float* __restrict__ ws) {
  int bid = blockIdx.x, tid = threadIdx.x;
  int w = tid >> 6, lane = tid & 63;
  __shared__ float tl2[2][64][65];               // transpose tiles (33.3 KB)

  if (bid < 512) {
    int row = bid * 8 + w;                       // 0..4095
    float4 v = ((const float4*)vf)[(size_t)row * 64 + lane];
    float s4 = v.x + v.y + v.z + v.w;
    for (int m = 32; m; m >>= 1) s4 += __shfl_xor(s4, m);
    if (lane == 0) ws[WS_VFMEAN + row] = s4 * (1.0f / HW_);
    return;
  }
  if (bid == 640) {
    float mx = -1e30f, mn = 1e30f;
    #pragma unroll
    for (int i = tid; i < N_ * D_; i += 512) {
      float v = te[i];
      mx = fmaxf(mx, v); mn = fminf(mn, v);
    }
    for (int m = 32; m; m >>= 1) {
      mx = fmaxf(mx, __shfl_xor(mx, m));
      mn = fminf(mn, __shfl_xor(mn, m));
    }
    __shared__ float rx[8], rn[8];
    if (lane == 0) { rx[w] = mx; rn[w] = mn; }
    __syncthreads();
    if (tid == 0) {
      float ax = rx[0], an = rn[0];
      #pragma unroll
      for (int k = 1; k < 8; ++k) { ax = fmaxf(ax, rx[k]); an = fminf(an, rn[k]); }
      ws[WS_TMAX] = ax; ws[WS_TMIN] = an;
    }
    return;
  }
  if (bid >= 641) {
    // transpose: 2 tiles per block, group g = tid>>8, t = tid&255
    int g = tid >> 8, t = tid & 255;
    int rr = t >> 4, cv = t & 15;
    const float* src; float* dst; int srcLD, r0, c0;
    if (bid < 705) {                             // iw: 128 tiles (8 x 16)
      int tile = (bid - 641) * 2 + g;
      src = iw; srcLD = 1024;
      dst = ws + WS_IWT;                         // [1024][512]
      r0 = (tile >> 4) * 64; c0 = (tile & 15) * 64;
    } else {                                     // vw: 32 tiles (8 x 4)
      int tile = (bid - 705) * 2 + g;
      src = vw; srcLD = 256;
      dst = ws + WS_VWT;                         // [256][512]
      r0 = (tile >> 2) * 64; c0 = (tile & 3) * 64;
    }
    float (*tl)[65] = tl2[g];
    #pragma unroll
    for (int it = 0; it < 4; ++it) {
      int r = rr + it * 16;
      f32x4 v = *(const f32x4*)(src + (size_t)(r0 + r) * srcLD + c0 + cv * 4);
      tl[r][cv * 4 + 0] = v.x; tl[r][cv * 4 + 1] = v.y;
      tl[r][cv * 4 + 2] = v.z; tl[r][cv * 4 + 3] = v.w;
    }
    __syncthreads();
    #pragma unroll
    for (int it = 0; it < 4; ++it) {
      int c = rr + it * 16;                      // src col = dst row
      f32x4 o;
      o.x = tl[cv * 4 + 0][c];
      o.y = tl[cv * 4 + 1][c];
      o.z = tl[cv * 4 + 2][c];
      o.w = tl[cv * 4 + 3][c];
      *(f32x4*)(dst + (size_t)(c0 + c) * 512 + r0 + cv * 4) = o;
    }
    return;
  }
  // s-partial block (byte-identical to R11)
  {
    int sidx = bid - 512;                        // 0..127
    int b = sidx >> 3, cc = sidx & 7;
    __shared__ float pcw[16][32];
    __shared__ float cw[32];
    __shared__ float sp2[2][256];
    __shared__ float sbr[8];

    if (cc == 0) {
      float v = vb[tid];
      for (int m = 32; m; m >>= 1) v += __shfl_xor(v, m);
      if (lane == 0) sbr[w] = v;
    }
    {
      int cl = tid & 31, dg = tid >> 5;
      int c = cc * 32 + cl;
      float a = 0.f;
      #pragma unroll 8
      for (int d = dg * 32; d < dg * 32 + 32; ++d) a += vw[d * C_ + c];
      pcw[dg][cl] = a;
    }
    __syncthreads();
    if (tid < 32) {
      float a = 0.f;
      #pragma unroll
      for (int k = 0; k < 16; ++k) a += pcw[k][tid];
      cw[tid] = a;
    }
    __syncthreads();
    {
      int hw = tid & 255, hf = tid >> 8;
      const float* vfb = vf + (size_t)b * C_ * HW_ + (size_t)(cc * 32 + hf * 16) * HW_;
      float acc = 0.f;
      #pragma unroll
      for (int k = 0; k < 16; ++k) acc += vfb[k * HW_ + hw] * cw[hf * 16 + k];
      sp2[hf][hw] = acc;
    }
    __syncthreads();
    if (tid < 256) {
      float s = sp2[0][tid] + sp2[1][tid];
      if (cc == 0) {
        float sbt = sbr[0];
        #pragma unroll
        for (int k = 1; k < 8; ++k) sbt += sbr[k];
        s += sbt;
      }
      ws[WS_SP + (b * 8 + cc) * 256 + tid] = s;
    }
  }
}

// ---------------- kZ: 544 blocks x 256 threads ----------------
// blocks 0..511  : Z partials (byte-identical to R11)
// blocks 512..543: vpmean via vwT (coalesced)
__global__ __launch_bounds__(256)
void kZ(const float* __restrict__ vb, const float* __restrict__ te,
        float* __restrict__ ws) {
  int bid = blockIdx.x, tid = threadIdx.x;
  if (bid < 512) {
    int b = bid >> 5, chunk = bid & 31;
    __shared__ __align__(16) float sl[HW_];
    __shared__ float r3[4], r4[4], part[4];
    float sv = 0.f;
    #pragma unroll
    for (int p = 0; p < 8; ++p) sv += ws[WS_SP + (b * 8 + p) * 256 + tid];
    sl[tid] = sv;
    float smx = sv, smn = sv;
    for (int m = 32; m; m >>= 1) {
      smx = fmaxf(smx, __shfl_xor(smx, m));
      smn = fminf(smn, __shfl_xor(smn, m));
    }
    int w = tid >> 6;
    if ((tid & 63) == 0) { r3[w] = smx; r4[w] = smn; }
    __syncthreads();
    smx = fmaxf(fmaxf(r3[0], r3[1]), fmaxf(r3[2], r3[3]));
    smn = fminf(fminf(r4[0], r4[1]), fminf(r4[2], r4[3]));
    float m = corner(ws[WS_TMAX], ws[WS_TMIN], smx, smn);
    if (chunk == 0) {
      ws[WS_S + b * HW_ + tid] = sv;
      if (tid == 0) ws[WS_M + b] = m;
    }
    float t = te[chunk * 256 + tid];
    const f32x4* sl4 = (const f32x4*)sl;
    float a0 = 0.f, a1 = 0.f, a2 = 0.f, a3 = 0.f;
    #pragma unroll 8
    for (int h = 0; h < HW_ / 4; ++h) {
      f32x4 s4 = sl4[h];
      a0 += __expf(t * s4.x - m);
      a1 += __expf(t * s4.y - m);
      a2 += __expf(t * s4.z - m);
      a3 += __expf(t * s4.w - m);
    }
    float z = (a0 + a1) + (a2 + a3);
    for (int mm = 32; mm; mm >>= 1) z += __shfl_xor(z, mm);
    if ((tid & 63) == 0) part[tid >> 6] = z;
    __syncthreads();
    if (tid == 0) ws[WS_ZP + bid] = part[0] + part[1] + part[2] + part[3];
    return;
  }
  // vpmean[b,dd] = sum_c vfm[c] * vwT[c][dd] + vb[dd]  (coalesced over dd)
  {
    int id = (bid - 512) * 256 + tid;            // 0..8191
    int b = id >> 9, dd = id & (D_ - 1);
    __shared__ float vfm[C_];
    vfm[tid] = ws[WS_VFMEAN + b * C_ + tid];
    __syncthreads();
    float a0 = 0.f, a1 = 0.f, a2 = 0.f, a3 = 0.f;
    const float* wt = ws + WS_VWT + dd;
    #pragma unroll 8
    for (int c = 0; c < C_; c += 4) {
      a0 += vfm[c]     * wt[(size_t)c * 512];
      a1 += vfm[c + 1] * wt[(size_t)(c + 1) * 512];
      a2 += vfm[c + 2] * wt[(size_t)(c + 2) * 512];
      a3 += vfm[c + 3] * wt[(size_t)(c + 3) * 512];
    }
    ws[WS_VPMEAN + id] = (a0 + a1) + (a2 + a3) + vb[dd];
  }
}

// ---------------- kD: final via iwT (0..31), attn (32..2079, R11-exact) ----
__global__ __launch_bounds__(256)
void kD(const float* __restrict__ te, const float* __restrict__ mtf,
        const float* __restrict__ ib, const float* __restrict__ ws,
        float* __restrict__ out) {
  int bid = blockIdx.x, tid = threadIdx.x;
  if (bid < 32) {
    // final[b,d] = sum_c comb[c] * iwT[c][d] + ib[d]   (coalesced over d)
    int b = bid >> 1, d = ((bid & 1) << 8) + tid;
    __shared__ float comb[2 * D_];
    comb[tid]       = mtf[b * D_ + tid];
    comb[tid + 256] = mtf[b * D_ + tid + 256];
    comb[tid + 512] = ws[WS_VPMEAN + b * D_ + tid];
    comb[tid + 768] = ws[WS_VPMEAN + b * D_ + tid + 256];
    __syncthreads();
    float a0 = 0.f, a1 = 0.f, a2 = 0.f, a3 = 0.f;
    const float* it4 = ws + WS_IWT + d;
    #pragma unroll 8
    for (int c = 0; c < 2 * D_; c += 4) {
      a0 += comb[c]     * it4[(size_t)c * 512];
      a1 += comb[c + 1] * it4[(size_t)(c + 1) * 512];
      a2 += comb[c + 2] * it4[(size_t)(c + 2) * 512];
      a3 += comb[c + 3] * it4[(size_t)(c + 3) * 512];
    }
    out[b * D_ + d] = (a0 + a1) + (a2 + a3) + ib[d];
    return;
  }
  // attn: 2048 blocks x 64 rows each, plain f32x4 stores (R11-exact)
  int r0 = (bid - 32) * 64;
  int b = r0 >> 13;
  __shared__ __align__(16) float sl[HW_];
  __shared__ float sinvZ;
  sl[tid] = ws[WS_S + b * HW_ + tid];
  if (tid < 32) {
    float pz = ws[WS_ZP + b * 32 + tid];
    #pragma unroll
    for (int m = 16; m; m >>= 1) pz += __shfl_xor(pz, m);
    if (tid == 0) sinvZ = 1.0f / pz;
  }
  __syncthreads();
  float m = ws[WS_M + b];
  float invZ = sinvZ;
  int lane = tid & 63;
  int w = tid >> 6;
  float4 sv = ((const float4*)sl)[lane];
  float* attn = out + N_ * D_;
  #pragma unroll 4
  for (int k = 0; k < 16; ++k) {
    int row = r0 + w + k * 4;
    float t = te[row & (N_ * D_ - 1)];
    f32x4 o;
    o.x = __expf(t * sv.x - m) * invZ;
    o.y = __expf(t * sv.y - m) * invZ;
    o.z = __expf(t * sv.z - m) * invZ;
    o.w = __expf(t * sv.w - m) * invZ;
    ((f32x4*)(attn + (size_t)row * HW_))[lane] = o;
  }
}

extern "C" void kernel_launch(void* const* d_in, const int* in_sizes, int n_in,
                              void* d_out, int out_size, void* d_ws, size_t ws_size,
                              hipStream_t stream) {
  const float* mtf = (const float*)d_in[0];  // masked_text_features [16,512]
  const float* vf  = (const float*)d_in[1];  // visual_features [16,256,16,16]
  const float* te  = (const float*)d_in[2];  // text_embeddings [16,512]
  const float* vw  = (const float*)d_in[3];  // visual_proj_w [512,256]
  const float* vb  = (const float*)d_in[4];  // visual_proj_b [512]
  const float* iw  = (const float*)d_in[5];  // interaction_w [512,1024]
  const float* ib  = (const float*)d_in[6];  // interaction_b [512]
  float* out = (float*)d_out;
  float* ws  = (float*)d_ws;

  kP<<<721,  512, 0, stream>>>(vf, vw, vb, te, iw, ws);
  kZ<<<544,  256, 0, stream>>>(vb, te, ws);
  kD<<<2080, 256, 0, stream>>>(te, mtf, ib, ws, out);
}